// Round 1
// baseline (842.976 us; speedup 1.0000x reference)
//
#include <hip/hip_runtime.h>

#define NB 2048      // query positions
#define NOBS 2048    // observed positions
#define NP 15        // poly features
#define NG 21        // graph features
#define NE 64        // graph dict columns
#define ND 256       // opd dim
#define NK 36        // NP + NG
#define NDD (ND*ND)  // 65536
#define ROWS 256     // row tile per block in expansion

// ---------------------------------------------------------------------------
// Kernel 1: per-query 1-NN over obs_pos + build 36-entry coefficient vector.
// grid = NB blocks x 256 threads. obs_pos staged in LDS (16 KB).
// ---------------------------------------------------------------------------
__global__ __launch_bounds__(256) void knn_coeff_kernel(
    const float* __restrict__ positions,   // [NB][2]
    const float* __restrict__ obs_pos,     // [NOBS][2]
    const float* __restrict__ poly_dic,    // [NOBS][NP]
    const float* __restrict__ graph_dic,   // [NOBS][NE]
    const float* __restrict__ alpha_poly,  // [NP][NP]
    const float* __restrict__ alpha_graph, // [NE][NG]
    float* __restrict__ coeff)             // [NB][NK]
{
    __shared__ float2 sobs[NOBS];
    __shared__ float  sd[256];
    __shared__ int    si[256];
    __shared__ int    sidx;

    const int tid = threadIdx.x;
    const int b   = blockIdx.x;

    const float2* obs2 = (const float2*)obs_pos;
    for (int i = tid; i < NOBS; i += 256) sobs[i] = obs2[i];

    const float qx = positions[2*b + 0];   // wave-uniform -> s_load
    const float qy = positions[2*b + 1];
    __syncthreads();

    // Each thread scans indices tid, tid+256, ... (ascending) -> strict '<'
    // keeps the earliest index within a thread, matching argmin-first.
    float bestd = 3.4e38f;
    int   besti = 0;
    #pragma unroll
    for (int it = 0; it < NOBS/256; ++it) {
        const int i = tid + it*256;
        const float dx = qx - sobs[i].x;
        const float dy = qy - sobs[i].y;
        const float d2 = dx*dx + dy*dy;
        if (d2 < bestd) { bestd = d2; besti = i; }
    }
    sd[tid] = bestd; si[tid] = besti;
    __syncthreads();

    // Tree reduction; on equal d2 prefer the smaller index (argmin-first).
    for (int s = 128; s > 0; s >>= 1) {
        if (tid < s) {
            const float d2 = sd[tid + s];
            const int   i2 = si[tid + s];
            if (d2 < sd[tid] || (d2 == sd[tid] && i2 < si[tid])) {
                sd[tid] = d2; si[tid] = i2;
            }
        }
        __syncthreads();
    }
    if (tid == 0) sidx = si[0];
    __syncthreads();
    const int idx = sidx;

    // coeff[b][0:15]  = poly_dic[idx] @ alpha_poly
    // coeff[b][15:36] = graph_dic[idx] @ alpha_graph
    if (tid < NP) {
        float acc = 0.f;
        #pragma unroll
        for (int q = 0; q < NP; ++q)
            acc += poly_dic[idx*NP + q] * alpha_poly[q*NP + tid];
        coeff[b*NK + tid] = acc;
    } else if (tid < NK) {
        const int g = tid - NP;
        float acc = 0.f;
        #pragma unroll
        for (int e = 0; e < NE; ++e)
            acc += graph_dic[idx*NE + e] * alpha_graph[e*NG + g];
        coeff[b*NK + tid] = acc;
    }
}

// ---------------------------------------------------------------------------
// Kernel 2: out[b][j] = sum_k coeff[b][k] * S_all[k][j]
// grid = (NDD/256, NB/ROWS) x 256 threads.
// Each thread keeps its 36 S values in VGPRs; coeff rows are wave-uniform
// scalar loads; 4 independent accumulator chains for ILP.
// ---------------------------------------------------------------------------
__global__ __launch_bounds__(256) void expand_kernel(
    const float* __restrict__ coeff,    // [NB][NK]
    const float* __restrict__ S_poly,   // [NP][NDD]
    const float* __restrict__ S_graph,  // [NG][NDD]
    float* __restrict__ out)            // [NB][NDD]
{
    const int j  = blockIdx.x * 256 + threadIdx.x;
    const int b0 = blockIdx.y * ROWS;

    float s[NK];
    #pragma unroll
    for (int k = 0; k < NP; ++k) s[k] = S_poly[(size_t)k*NDD + j];
    #pragma unroll
    for (int k = 0; k < NG; ++k) s[NP + k] = S_graph[(size_t)k*NDD + j];

    for (int bb = 0; bb < ROWS; bb += 4) {
        const float* __restrict__ c0 = coeff + (size_t)(b0 + bb)*NK;  // uniform
        float a0 = 0.f, a1 = 0.f, a2 = 0.f, a3 = 0.f;
        #pragma unroll
        for (int k = 0; k < NK; ++k) {
            const float sk = s[k];
            a0 += c0[k         ] * sk;
            a1 += c0[NK   + k  ] * sk;
            a2 += c0[2*NK + k  ] * sk;
            a3 += c0[3*NK + k  ] * sk;
        }
        size_t base = (size_t)(b0 + bb)*NDD + j;
        out[base         ] = a0;
        out[base +   NDD ] = a1;
        out[base + 2*NDD ] = a2;
        out[base + 3*NDD ] = a3;
    }
}

extern "C" void kernel_launch(void* const* d_in, const int* in_sizes, int n_in,
                              void* d_out, int out_size, void* d_ws, size_t ws_size,
                              hipStream_t stream) {
    const float* positions   = (const float*)d_in[0];
    const float* obs_pos     = (const float*)d_in[1];
    const float* poly_dic    = (const float*)d_in[2];
    const float* graph_dic   = (const float*)d_in[3];
    const float* alpha_poly  = (const float*)d_in[4];
    const float* alpha_graph = (const float*)d_in[5];
    const float* S_poly      = (const float*)d_in[6];
    const float* S_graph     = (const float*)d_in[7];
    float* out = (float*)d_out;

    float* coeff = (float*)d_ws;   // NB*NK floats = 288 KB

    knn_coeff_kernel<<<NB, 256, 0, stream>>>(
        positions, obs_pos, poly_dic, graph_dic, alpha_poly, alpha_graph, coeff);

    dim3 grid2(NDD/256, NB/ROWS);
    expand_kernel<<<grid2, 256, 0, stream>>>(coeff, S_poly, S_graph, out);
}